// Round 16
// baseline (448.564 us; speedup 1.0000x reference)
//
#include <hip/hip_runtime.h>
#include <hip/hip_bf16.h>
#include <math.h>

typedef __hip_bfloat16 bf16;
typedef __attribute__((ext_vector_type(8))) short short8;   // 8 x bf16 MFMA frag
typedef __attribute__((ext_vector_type(4))) float floatx4;  // 4 x f32 MFMA acc

// Problem constants: B=64, DIM=256, HID=512, NH=4, KD=16, D=64, 28x28, WH=7
#define BB    64
#define DIMC  256
#define HIDC  512
#define NHH   4
#define HH_   28
#define WW_   28
#define PP    784   // 28*28

__device__ __forceinline__ float toF(bf16 x) { return __bfloat162float(x); }
__device__ __forceinline__ unsigned short f2bits(float f) {
    union { bf16 h; unsigned short u; } cv; cv.h = __float2bfloat16(f); return cv.u;
}
__device__ __forceinline__ float bits2f(unsigned short u) {
    union { unsigned int u32; float f; } cv; cv.u32 = ((unsigned int)u) << 16; return cv.f;
}

// async 16B global -> LDS (wave-uniform LDS base + lane*16; vmcnt-counted)
__device__ __forceinline__ void gll16(const void* g, void* l) {
    __builtin_amdgcn_global_load_lds(
        (const __attribute__((address_space(1))) void*)g,
        (__attribute__((address_space(3))) void*)l, 16, 0, 0);
}

// ---------------------------------------------------------------------------
// fp32 -> bf16 weight convert — single merged launch for all 6 weight arrays
// ---------------------------------------------------------------------------
__global__ __launch_bounds__(256) void cvt_all(
    const float* __restrict__ s0, bf16* __restrict__ d0,   // 131072
    const float* __restrict__ s1, bf16* __restrict__ d1,   // 131072
    const float* __restrict__ s2, bf16* __restrict__ d2,   // 131072
    const float* __restrict__ s3, bf16* __restrict__ d3,   // 131072
    const float* __restrict__ s4, bf16* __restrict__ d4,   // 98304
    const float* __restrict__ s5, bf16* __restrict__ d5)   // 65536
{
    int i = blockIdx.x * 256 + threadIdx.x;
    if (i < 131072)                d0[i]          = __float2bfloat16(s0[i]);
    else if (i < 262144)           d1[i - 131072] = __float2bfloat16(s1[i - 131072]);
    else if (i < 393216)           d2[i - 262144] = __float2bfloat16(s2[i - 262144]);
    else if (i < 524288)           d3[i - 393216] = __float2bfloat16(s3[i - 393216]);
    else if (i < 622592)           d4[i - 524288] = __float2bfloat16(s4[i - 524288]);
    else if (i < 688128)           d5[i - 622592] = __float2bfloat16(s5[i - 622592]);
}

// ---------------------------------------------------------------------------
// Depthwise 3x3 conv + BN + residual -> bf16 NHWC mirror — ROUND-15:
// NHWCIN variant added. dw1's fp32 NCHW input existed only because proj wrote
// it; proj now writes bf16 NHWC (X3b), and dw1 stages its 4-channel planes
// from NHWC via one uint2/pixel (the 64 co-XCD cgroup blocks of an image
// collectively consume full cache lines — same locality as the proven mirror
// write). Saves proj 25.7 MB write + dw1 25.7 MB read.
// Register shfl transpose for the NHWC pack; halo-only zero (strided);
// 14.4 KB LDS, 1 barrier. grid (64 cgroups, BB), chunked-XCD remap, block 256.
// ---------------------------------------------------------------------------
#define CPB 4
template <bool WF, bool NHWCIN>
__global__ __launch_bounds__(256) void dw3x3_kernel(
    const float* __restrict__ inF, const bf16* __restrict__ inB,
    const float* __restrict__ w,
    const float* __restrict__ s, const float* __restrict__ b,
    float* __restrict__ out, bf16* __restrict__ outB)
{
    __shared__ float t[CPB][30 * 30];        // padded planes, zero halo

    // chunked-XCD bijective remap: one image's 64 cgroups contiguous per XCD
    int wid = blockIdx.y * gridDim.x + blockIdx.x;         // 0..4095
    int lin = (wid & 7) * 512 + (wid >> 3);                // 4096/8 = 512
    int cg  = lin & 63;
    int n   = lin >> 6;
    int c0  = cg * CPB;

    int tid = threadIdx.x;
    int lm  = tid & 3;                       // this thread's channel (c0+lm)
    float* op = out + ((size_t)n * DIMC + c0) * PP;

    // per-thread channel weights (global scalar loads, L1/L2-cached)
    float w9[9];
#pragma unroll
    for (int i = 0; i < 9; i++) w9[i] = w[(c0 + lm) * 9 + i];
    float sc = s[c0 + lm], bb = b[c0 + lm];

    // zero HALO cells only (116/plane x 4 = 464) — strided over the block
    for (int i = tid; i < 464; i += 256) {
        int plane = i / 116, bq = i - plane * 116;
        int cell;
        if (bq < 30)       cell = bq;                       // top row
        else if (bq < 60)  cell = 870 + (bq - 30);          // bottom row
        else if (bq < 88)  cell = (bq - 60 + 1) * 30;       // left col r=1..28
        else               cell = (bq - 88 + 1) * 30 + 29;  // right col
        t[plane][cell] = 0.f;
    }
    // stage interior
    if (NHWCIN) {
        const unsigned short* ib = (const unsigned short*)inB;
        for (int p = tid; p < PP; p += 256) {
            int h = p / 28, x = p - h * 28;
            union { uint2 u; unsigned short hb[4]; } v;
            v.u = *(const uint2*)&ib[((size_t)n * PP + p) * DIMC + c0];
            int cell = (h + 1) * 30 + (x + 1);
#pragma unroll
            for (int ch = 0; ch < CPB; ch++) t[ch][cell] = bits2f(v.hb[ch]);
        }
    } else {
        const float* ip = inF + ((size_t)n * DIMC + c0) * PP;
        for (int idx = tid; idx < CPB * 196; idx += 256) {
            int ch  = idx / 196;
            int rm  = idx - ch * 196;
            int row = rm / 7, seg = rm - row * 7;
            float4 v = *(const float4*)&ip[ch * PP + row * 28 + seg * 4];
            float* dst = &t[ch][(row + 1) * 30 + seg * 4 + 1];
            dst[0] = v.x; dst[1] = v.y; dst[2] = v.z; dst[3] = v.w;
        }
    }
    __syncthreads();

    // compute: px-major tasks; idx&3 == lm (256 % 4 == 0)
    unsigned short* oBu = (unsigned short*)outB;
    for (int idx = tid; idx < CPB * 196; idx += 256) {
        int rm  = idx >> 2;
        int row = rm / 7, seg = rm - row * 7;
        int x0  = seg * 4;

        float acc[4] = {0.f, 0.f, 0.f, 0.f};
        float ctr[4];
        const float* base = &t[lm][row * 30 + x0];
#pragma unroll
        for (int i = 0; i < 3; i++) {
            float r[6];
#pragma unroll
            for (int k = 0; k < 6; k++) r[k] = base[i * 30 + k];
            if (i == 1) { ctr[0] = r[1]; ctr[1] = r[2]; ctr[2] = r[3]; ctr[3] = r[4]; }
#pragma unroll
            for (int j = 0; j < 3; j++)
#pragma unroll
                for (int q = 0; q < 4; q++)
                    acc[q] += w9[i * 3 + j] * r[j + q];
        }
        float v0 = ctr[0] + acc[0] * sc + bb;
        float v1 = ctr[1] + acc[1] * sc + bb;
        float v2 = ctr[2] + acc[2] * sc + bb;
        float v3 = ctr[3] + acc[3] * sc + bb;

        if (WF) {   // fp32 NCHW write (only when a consumer needs it)
            float4 o; o.x = v0; o.y = v1; o.z = v2; o.w = v3;
            *(float4*)&op[lm * PP + row * 28 + x0] = o;
        }

        // 4x4 transpose across the 4-lane group (static indices only)
        float ea = __shfl_xor((lm & 2) ? v0 : v2, 2);
        float eb = __shfl_xor((lm & 2) ? v1 : v3, 2);
        v0 = (lm & 2) ? ea : v0;  v1 = (lm & 2) ? eb : v1;
        v2 = (lm & 2) ? v2 : ea;  v3 = (lm & 2) ? v3 : eb;
        float ec = __shfl_xor((lm & 1) ? v0 : v1, 1);
        float ed = __shfl_xor((lm & 1) ? v2 : v3, 1);
        v0 = (lm & 1) ? ec : v0;  v1 = (lm & 1) ? v1 : ec;
        v2 = (lm & 1) ? ed : v2;  v3 = (lm & 1) ? v3 : ed;
        // lane q holds channels c0..c0+3 of pixel row*28 + x0 + q
        int p = row * 28 + x0 + lm;
        union { unsigned short h[4]; uint2 u; } pk;
        pk.h[0] = f2bits(v0); pk.h[1] = f2bits(v1);
        pk.h[2] = f2bits(v2); pk.h[3] = f2bits(v3);
        *(uint2*)&oBu[((size_t)n * PP + p) * DIMC + c0] = pk.u;
    }
}

// ---------------------------------------------------------------------------
// Per-head depthwise 5x5 + BN on q channels — round-5 LDS version (proven).
// grid (NHH, BB), block 256, LDS 32 KB.
// ---------------------------------------------------------------------------
__global__ __launch_bounds__(256) void dws5x5_nhwc(
    const bf16* __restrict__ qkv,   // [64][784][384]
    const float* __restrict__ w,    // [64][25]  (hk-major)
    const float* __restrict__ s, const float* __restrict__ b,
    bf16* __restrict__ qout)        // [64][784][64]
{
    __shared__ __align__(16) unsigned short qin[32 * 32 * 16];  // [r][c][ch]
    int hh  = blockIdx.x;
    int n   = blockIdx.y;
    int tid = threadIdx.x;
    const unsigned short* KVu = (const unsigned short*)qkv;

    int kcw = tid & 15;
    int hk  = hh * 16 + kcw;
    float w25[25];
#pragma unroll
    for (int i = 0; i < 25; i++) w25[i] = w[hk * 25 + i];
    float csc = s[hk], cbb = b[hk];

    // zero-fill (halo must be 0), then stage interior
    for (int i = tid; i < 4096; i += 256)
        ((uint4*)qin)[i] = make_uint4(0u, 0u, 0u, 0u);
    __syncthreads();
    for (int idx = tid; idx < 1568; idx += 256) {
        int p = idx >> 1, half = idx & 1;
        int h = p / 28, x = p - h * 28;
        uint4 v = *(const uint4*)&KVu[((size_t)n * PP + p) * 384 + hh * 96 + half * 8];
        *(uint4*)&qin[((h + 2) * 32 + (x + 2)) * 16 + half * 8] = v;
    }
    __syncthreads();

    // compute: 784 px x 16 ch tasks
    for (int idx = tid; idx < 12544; idx += 256) {
        int p = idx >> 4;            // channel == kcw since 256 % 16 == 0
        int h = p / 28, x = p - h * 28;
        float acc = 0.f;
#pragma unroll
        for (int i = 0; i < 5; i++)
#pragma unroll
            for (int j = 0; j < 5; j++)
                acc += w25[i * 5 + j] * bits2f(qin[((h + i) * 32 + (x + j)) * 16 + kcw]);
        qout[((size_t)n * PP + p) * 64 + hk] = __float2bfloat16(acc * csc + cbb);
    }
}

// ---------------------------------------------------------------------------
// 1x1 conv as bf16 MFMA GEMM — gll staging + XCD swizzle + RESMODE 2 (proven).
// RESMODE: 0 none | 1 fp32 NCHW | 2 bf16 NHWC.
// OUTMODE: 0 bf16 NHWC | 1 fp32 NCHW | 2 both.       grid (7, M/64, 64)
// ---------------------------------------------------------------------------
template <bool RELU, int RESMODE, int OUTMODE>
__global__ __launch_bounds__(256) void gemm_mfma(
    const bf16* __restrict__ Wb,    // [M][K] bf16
    const bf16* __restrict__ X,     // [64][784][K] bf16 NHWC
    const float* __restrict__ S, const float* __restrict__ Bb,
    const float* __restrict__ resF, // [64][M][784] fp32 NCHW (RESMODE 1)
    const bf16*  __restrict__ resB, // [64][784][M] bf16 NHWC (RESMODE 2)
    float* __restrict__ outF,       // fp32 NCHW (OUTMODE 1/2)
    bf16*  __restrict__ outB,       // bf16 NHWC (OUTMODE 0/2)
    int M, int K)
{
    // chunked-XCD bijective remap (nwg % 8 == 0 for all instantiations)
    int nwg = gridDim.x * gridDim.y * gridDim.z;
    int wid = (blockIdx.z * gridDim.y + blockIdx.y) * gridDim.x + blockIdx.x;
    int lin = (wid & 7) * (nwg >> 3) + (wid >> 3);
    int yb  = lin % gridDim.y;             // co-tile (fastest: shares X panel)
    int t2  = lin / gridDim.y;
    int xb  = t2 % gridDim.x;              // p-tile
    int n   = t2 / gridDim.x;              // image

    int co0  = yb * 64;
    int p0   = xb * 112;
    int tid  = threadIdx.x;
    int wv   = tid >> 6;
    int ln   = tid & 63;
    int l15  = ln & 15;
    int quad = ln >> 4;

    __shared__ __align__(16) unsigned short Blds[2][112 * 32];  // linear 64B rows

    floatx4 acc[7];
#pragma unroll
    for (int t = 0; t < 7; t++) acc[t] = (floatx4){0.f, 0.f, 0.f, 0.f};

    const bf16* Arow = Wb + (size_t)(co0 + wv * 16 + l15) * K + quad * 8;
    const unsigned short* Xb = (const unsigned short*)X + ((size_t)n * PP + p0) * K;

    // staging geometry: issue A covers rows 0..63 (all waves), issue B rows
    // 64..111 (waves 0..2). dest = wave-uniform LDS base + lane*16.
    int rA = wv * 16 + (ln >> 2);            // 0..63
    int rB = 64 + wv * 16 + (ln >> 2);       // 64..111 (wv<3)
    int cA = (ln & 3) ^ ((rA >> 1) & 3);     // pre-swizzled source chunk
    int cB = (ln & 3) ^ ((rB >> 1) & 3);
    const unsigned short* gA = Xb + (size_t)rA * K + cA * 8;
    const unsigned short* gB = Xb + (size_t)rB * K + cB * 8;

    // prologue: stage tile 0
    gll16(gA, &Blds[0][(wv * 16) * 32]);
    if (wv < 3) gll16(gB, &Blds[0][(64 + wv * 16) * 32]);
    short8 af = *(const short8*)Arow;
    __syncthreads();

    int NT = K >> 5;
    for (int t = 0; t < NT; t++) {
        int cur = t & 1;
        short8 naf = af;
        if (t + 1 < NT) {
            gll16(gA + (t + 1) * 32, &Blds[cur ^ 1][(wv * 16) * 32]);
            if (wv < 3) gll16(gB + (t + 1) * 32, &Blds[cur ^ 1][(64 + wv * 16) * 32]);
            naf = *(const short8*)(Arow + (t + 1) * 32);
        }
#pragma unroll
        for (int tt = 0; tt < 7; tt++) {
            int row = tt * 16 + l15;
            short8 bfrag = *(const short8*)
                &Blds[cur][row * 32 + ((quad ^ ((row >> 1) & 3)) * 8)];
            acc[tt] = __builtin_amdgcn_mfma_f32_16x16x32_bf16(af, bfrag, acc[tt], 0, 0, 0);
        }
        af = naf;
        __syncthreads();   // vmcnt(0) drain (stage done) + reads of buf[cur] done
    }

    int cobase = co0 + wv * 16 + quad * 4;
    float s4[4], b4[4];
#pragma unroll
    for (int r = 0; r < 4; r++) { s4[r] = S[cobase + r]; b4[r] = Bb[cobase + r]; }

#pragma unroll
    for (int t = 0; t < 7; t++) {
        int p = p0 + t * 16 + l15;   // always < 784
        float resv[4] = {0.f, 0.f, 0.f, 0.f};
        if (RESMODE == 1) {
#pragma unroll
            for (int r = 0; r < 4; r++)
                resv[r] = resF[((size_t)n * M + cobase + r) * PP + p];
        }
        if (RESMODE == 2) {
            union { uint2 u; unsigned short h[4]; } rr;
            rr.u = *(const uint2*)((const unsigned short*)resB +
                                   ((size_t)n * PP + p) * M + cobase);
#pragma unroll
            for (int r = 0; r < 4; r++) resv[r] = bits2f(rr.h[r]);
        }
        float y[4];
#pragma unroll
        for (int r = 0; r < 4; r++) {
            y[r] = acc[t][r] * s4[r] + b4[r];
            if (RELU) y[r] = fmaxf(y[r], 0.f);
            if (RESMODE != 0) y[r] += resv[r];
        }
        if (OUTMODE == 1 || OUTMODE == 2) {
#pragma unroll
            for (int r = 0; r < 4; r++)
                outF[((size_t)n * M + cobase + r) * PP + p] = y[r];
        }
        if (OUTMODE == 0 || OUTMODE == 2) {
            union { unsigned short h4[4]; uint2 u; } pk;
#pragma unroll
            for (int r = 0; r < 4; r++) pk.h4[r] = f2bits(y[r]);
            *(uint2*)((unsigned short*)outB + ((size_t)n * PP + p) * M + cobase) = pk.u;
        }
    }
}

// ---------------------------------------------------------------------------
// 7x7 window attention — round-1 MFMA version (proven).
// grid (8, 4, 64), block 256.
// ---------------------------------------------------------------------------
__global__ __launch_bounds__(256) void attn_kernel(
    const bf16*  __restrict__ Q,       // [64][784][64] NHWC (hk = hh*16+kc)
    const bf16*  __restrict__ KV,      // [64][784][384] NHWC
    const float* __restrict__ pos,     // [4][49][49]
    bf16* __restrict__ O)              // [64][784][256] NHWC (c = hh*64+d)
{
    int wjp = blockIdx.x & 1, wi = blockIdx.x >> 1;
    int hh  = blockIdx.y, n = blockIdx.z;
    int tid = threadIdx.x;
    int pbase = wi * 7 * 28 + wjp * 14;

    __shared__ __align__(16) char smem[51712];
    unsigned short* qS = (unsigned short*)smem;              // [2][64][40]
    unsigned short* kS = qS + 2 * 64 * 40;                   // [2][64][40]
    unsigned short* pS = (unsigned short*)smem;              // alias: [2][64][72]
    unsigned short* vT = (unsigned short*)(smem + 20480);    // [2][64][72]
    float*          posL = (float*)(smem + 20480 + 18432);   // [64][50]

    const unsigned short* Qu  = (const unsigned short*)Q;
    const unsigned short* KVu = (const unsigned short*)KV;

    // ---- load q, k: 2 bufs x 2 windows x 64 rows x 5 halves (zero-padded) ----
    for (int idx = tid; idx < 1280; idx += 256) {
        int which = idx >= 640 ? 1 : 0;
        int t2 = idx - which * 640;
        int w = t2 / 320, rm = t2 - w * 320;
        int row = rm / 5, half = rm - row * 5;
        uint4 v = make_uint4(0u, 0u, 0u, 0u);
        if (row < 49 && half < 2) {
            int p = pbase + (row / 7) * 28 + w * 7 + (row % 7);
            const unsigned short* src = which
                ? &KVu[((size_t)n * PP + p) * 384 + hh * 96 + 16 + half * 8]
                : &Qu[((size_t)n * PP + p) * 64 + hh * 16 + half * 8];
            v = *(const uint4*)src;
        }
        *(uint4*)((which ? kS : qS) + (w * 64 + row) * 40 + half * 8) = v;
    }
    // ---- stage V transposed: vT[w][d][ki], zero cols for ki >= 49 ----
    for (int idx = tid; idx < 1024; idx += 256) {
        int w = idx >> 9, rm = idx & 511;
        int ki = rm >> 3, dq = rm & 7;
        union { uint4 q; unsigned short h[8]; } v;
        v.q = make_uint4(0u, 0u, 0u, 0u);
        if (ki < 49) {
            int p = pbase + (ki / 7) * 28 + w * 7 + (ki % 7);
            v.q = *(const uint4*)&KVu[((size_t)n * PP + p) * 384 + hh * 96 + 32 + dq * 8];
        }
#pragma unroll
        for (int j = 0; j < 8; j++)
            vT[(w * 64 + dq * 8 + j) * 72 + ki] = v.h[j];
    }
    // ---- stage pos [64][50], zero-padded ----
    for (int idx = tid; idx < 3200; idx += 256) {
        int r = idx / 50, c = idx - r * 50;
        posL[idx] = (r < 49 && c < 49) ? pos[((size_t)hh * 49 + r) * 49 + c] : 0.f;
    }
    __syncthreads();

    int wv = tid >> 6, ln = tid & 63, l15 = ln & 15, quad = ln >> 4;

    // ---- S^T via MFMA + in-register softmax; hold packed bf16 P ----
    uint2 pk[2][4];
#pragma unroll
    for (int w = 0; w < 2; w++) {
        short8 qf = *(const short8*)&qS[(w * 64 + wv * 16 + l15) * 40 + quad * 8];
        floatx4 a4[4];
#pragma unroll
        for (int kt = 0; kt < 4; kt++) {
            short8 kf = *(const short8*)&kS[(w * 64 + kt * 16 + l15) * 40 + quad * 8];
            a4[kt] = __builtin_amdgcn_mfma_f32_16x16x32_bf16(
                kf, qf, (floatx4){0.f, 0.f, 0.f, 0.f}, 0, 0, 0);
        }
        int q = wv * 16 + l15;
        float sv[16];
        float m = -1e30f;
#pragma unroll
        for (int kt = 0; kt < 4; kt++) {
#pragma unroll
            for (int r = 0; r < 4; r++) {
                int ki = kt * 16 + quad * 4 + r;
                float sc = (ki < 49)
                    ? a4[kt][r] * 0.25f + posL[q * 50 + ki]
                    : -1e30f;
                sv[kt * 4 + r] = sc;
                m = fmaxf(m, sc);
            }
        }
        m = fmaxf(m, __shfl_xor(m, 16));
        m = fmaxf(m, __shfl_xor(m, 32));
        float sum = 0.f;
#pragma unroll
        for (int i = 0; i < 16; i++) { sv[i] = __expf(sv[i] - m); sum += sv[i]; }
        sum += __shfl_xor(sum, 16);
        sum += __shfl_xor(sum, 32);
        float inv = 1.f / sum;
#pragma unroll
        for (int kt = 0; kt < 4; kt++) {
            union { uint2 u; unsigned short h[4]; } pku;
#pragma unroll
            for (int r = 0; r < 4; r++) pku.h[r] = f2bits(sv[kt * 4 + r] * inv);
            pk[w][kt] = pku.u;
        }
    }
    __syncthreads();   // all qS/kS MFMA reads done before aliasing writes

    {
        int q = wv * 16 + l15;
#pragma unroll
        for (int w = 0; w < 2; w++)
#pragma unroll
            for (int kt = 0; kt < 4; kt++)
                *(uint2*)&pS[(w * 64 + q) * 72 + kt * 16 + quad * 4] = pk[w][kt];
    }
    __syncthreads();

    // ---- O = relu(P @ V) via MFMA ----
    unsigned short* Ou = (unsigned short*)O;
#pragma unroll
    for (int w = 0; w < 2; w++) {
        short8 af0 = *(const short8*)&pS[(w * 64 + wv * 16 + l15) * 72 + quad * 8];
        short8 af1 = *(const short8*)&pS[(w * 64 + wv * 16 + l15) * 72 + 32 + quad * 8];
#pragma unroll
        for (int dt = 0; dt < 4; dt++) {
            floatx4 oacc = (floatx4){0.f, 0.f, 0.f, 0.f};
            short8 vf0 = *(const short8*)&vT[(w * 64 + dt * 16 + l15) * 72 + quad * 8];
            short8 vf1 = *(const short8*)&vT[(w * 64 + dt * 16 + l15) * 72 + 32 + quad * 8];
            oacc = __builtin_amdgcn_mfma_f32_16x16x32_bf16(af0, vf0, oacc, 0, 0, 0);
            oacc = __builtin_amdgcn_mfma_f32_16x16x32_bf16(af1, vf1, oacc, 0, 0, 0);
#pragma unroll
            for (int r = 0; r < 4; r++) {
                int q = wv * 16 + quad * 4 + r;
                if (q < 49) {
                    int p = pbase + (q / 7) * 28 + w * 7 + (q % 7);
                    Ou[((size_t)n * PP + p) * 256 + hh * 64 + dt * 16 + l15] =
                        f2bits(fmaxf(oacc[r], 0.f));
                }
            }
        }
    }
}

// ---------------------------------------------------------------------------
extern "C" void kernel_launch(void* const* d_in, const int* in_sizes, int n_in,
                              void* d_out, int out_size, void* d_ws, size_t ws_size,
                              hipStream_t stream)
{
    const float* x0     = (const float*)d_in[0];
    const float* dw0_w  = (const float*)d_in[1];
    const float* dw0_s  = (const float*)d_in[2];
    const float* dw0_b  = (const float*)d_in[3];
    const float* dw1_w  = (const float*)d_in[4];
    const float* dw1_s  = (const float*)d_in[5];
    const float* dw1_b  = (const float*)d_in[6];
    const float* f0w1   = (const float*)d_in[7];
    const float* f0s1   = (const float*)d_in[8];
    const float* f0b1   = (const float*)d_in[9];
    const float* f0w2   = (const float*)d_in[10];
    const float* f0s2   = (const float*)d_in[11];
    const float* f0b2   = (const float*)d_in[12];
    const float* f1w1   = (const float*)d_in[13];
    const float* f1s1   = (const float*)d_in[14];
    const float* f1b1   = (const float*)d_in[15];
    const float* f1w2   = (const float*)d_in[16];
    const float* f1s2   = (const float*)d_in[17];
    const float* f1b2   = (const float*)d_in[18];
    const float* qkv_w  = (const float*)d_in[19];
    const float* qkv_s  = (const float*)d_in[20];
    const float* qkv_b  = (const float*)d_in[21];
    const float* dws_w  = (const float*)d_in[22];
    const float* dws_s  = (const float*)d_in[23];
    const float* dws_b  = (const float*)d_in[24];
    const float* proj_w = (const float*)d_in[25];
    const float* proj_s = (const float*)d_in[26];
    const float* proj_b = (const float*)d_in[27];
    const float* pos    = (const float*)d_in[28];

    // -------- workspace (aliased) --------
    const size_t NXB = (size_t)BB * DIMC * PP * 4;    // 51,380,224 B
    char* base  = (char*)d_ws;
    bf16*  X3b  = (bf16*)base;                         // proj out (x3), 25.7 MB
    bf16*  Hb   = (bf16*)(base + NXB);
    bf16*  Qb   = Hb;                                  // alias, disjoint in time
    char*  C_   = base + 2 * NXB;
    bf16*  QKVb = (bf16*)C_;
    bf16*  X1b  = (bf16*)(base + 3 * NXB);             // 25.7 MB
    bf16*  Wc   = (bf16*)(base + 3 * NXB + NXB / 2);
    bf16*  Ob   = (bf16*)d_out;
    float* outp = (float*)d_out;

    bf16* Wf0w1 = Wc;                  // [512][256]
    bf16* Wf0w2 = Wf0w1 + 131072;      // [256][512]
    bf16* Wf1w1 = Wf0w2 + 131072;      // [512][256]
    bf16* Wf1w2 = Wf1w1 + 131072;      // [256][512]
    bf16* Wqkv  = Wf1w2 + 131072;      // [384][256]
    bf16* Wproj = Wqkv + 98304;        // [256][256]

    dim3 blk(256);

    // 0) weights fp32 -> bf16 (single merged launch)
    cvt_all<<<2688, blk, 0, stream>>>(f0w1, Wf0w1, f0w2, Wf0w2,
                                      f1w1, Wf1w1, f1w2, Wf1w2,
                                      qkv_w, Wqkv, proj_w, Wproj);

    // 1) x1 = x + dw0(x) -> bf16 NHWC mirror only (fp32 input)
    dw3x3_kernel<false, false><<<dim3(DIMC / CPB, BB), blk, 0, stream>>>(
        x0, nullptr, dw0_w, dw0_s, dw0_b, nullptr, X1b);

    // 2-3) ffn0: w2 res from X1b (bf16), writes X1b in-place (bf16 only)
    gemm_mfma<true, 0, 0><<<dim3(7, HIDC / 64, BB), blk, 0, stream>>>(
        Wf0w1, X1b, f0s1, f0b1, nullptr, nullptr, nullptr, Hb, HIDC, DIMC);
    gemm_mfma<false, 2, 0><<<dim3(7, DIMC / 64, BB), blk, 0, stream>>>(
        Wf0w2, Hb, f0s2, f0b2, nullptr, X1b, nullptr, X1b, DIMC, HIDC);

    // 4-7) attention; proj res from X1b (x2), OUT bf16 NHWC -> X3b (x3)
    gemm_mfma<false, 0, 0><<<dim3(7, 384 / 64, BB), blk, 0, stream>>>(
        Wqkv, X1b, qkv_s, qkv_b, nullptr, nullptr, nullptr, QKVb, 384, DIMC);
    dws5x5_nhwc<<<dim3(NHH, BB), blk, 0, stream>>>(QKVb, dws_w, dws_s, dws_b, Qb);
    attn_kernel<<<dim3(8, NHH, BB), blk, 0, stream>>>(Qb, QKVb, pos, Ob);
    gemm_mfma<false, 2, 0><<<dim3(7, DIMC / 64, BB), blk, 0, stream>>>(
        Wproj, Ob, proj_s, proj_b, nullptr, X1b, nullptr, X3b, DIMC, DIMC);

    // 8) x4 = x3 + dw1(x3): NHWC bf16 input (X3b), mirror -> X1b
    dw3x3_kernel<false, true><<<dim3(DIMC / CPB, BB), blk, 0, stream>>>(
        nullptr, X3b, dw1_w, dw1_s, dw1_b, nullptr, X1b);

    // 9-10) ffn1: w2 res from X1b, final fp32 NCHW to d_out
    gemm_mfma<true, 0, 0><<<dim3(7, HIDC / 64, BB), blk, 0, stream>>>(
        Wf1w1, X1b, f1s1, f1b1, nullptr, nullptr, nullptr, Hb, HIDC, DIMC);
    gemm_mfma<false, 2, 1><<<dim3(7, DIMC / 64, BB), blk, 0, stream>>>(
        Wf1w2, Hb, f1s2, f1b2, nullptr, X1b, outp, nullptr, DIMC, HIDC);
}

// Round 18
// 442.077 us; speedup vs baseline: 1.0147x; 1.0147x over previous
//
#include <hip/hip_runtime.h>
#include <hip/hip_bf16.h>
#include <math.h>

typedef __hip_bfloat16 bf16;
typedef __attribute__((ext_vector_type(8))) short short8;   // 8 x bf16 MFMA frag
typedef __attribute__((ext_vector_type(4))) float floatx4;  // 4 x f32 MFMA acc

// Problem constants: B=64, DIM=256, HID=512, NH=4, KD=16, D=64, 28x28, WH=7
#define BB    64
#define DIMC  256
#define HIDC  512
#define NHH   4
#define HH_   28
#define WW_   28
#define PP    784   // 28*28

__device__ __forceinline__ float toF(bf16 x) { return __bfloat162float(x); }
__device__ __forceinline__ unsigned short f2bits(float f) {
    union { bf16 h; unsigned short u; } cv; cv.h = __float2bfloat16(f); return cv.u;
}
__device__ __forceinline__ float bits2f(unsigned short u) {
    union { unsigned int u32; float f; } cv; cv.u32 = ((unsigned int)u) << 16; return cv.f;
}

// async 16B global -> LDS (wave-uniform LDS base + lane*16; vmcnt-counted)
__device__ __forceinline__ void gll16(const void* g, void* l) {
    __builtin_amdgcn_global_load_lds(
        (const __attribute__((address_space(1))) void*)g,
        (__attribute__((address_space(3))) void*)l, 16, 0, 0);
}

// ---------------------------------------------------------------------------
// fp32 -> bf16 weight convert — single merged launch for all 6 weight arrays
// ---------------------------------------------------------------------------
__global__ __launch_bounds__(256) void cvt_all(
    const float* __restrict__ s0, bf16* __restrict__ d0,   // 131072
    const float* __restrict__ s1, bf16* __restrict__ d1,   // 131072
    const float* __restrict__ s2, bf16* __restrict__ d2,   // 131072
    const float* __restrict__ s3, bf16* __restrict__ d3,   // 131072
    const float* __restrict__ s4, bf16* __restrict__ d4,   // 98304
    const float* __restrict__ s5, bf16* __restrict__ d5)   // 65536
{
    int i = blockIdx.x * 256 + threadIdx.x;
    if (i < 131072)                d0[i]          = __float2bfloat16(s0[i]);
    else if (i < 262144)           d1[i - 131072] = __float2bfloat16(s1[i - 131072]);
    else if (i < 393216)           d2[i - 262144] = __float2bfloat16(s2[i - 262144]);
    else if (i < 524288)           d3[i - 393216] = __float2bfloat16(s3[i - 393216]);
    else if (i < 622592)           d4[i - 524288] = __float2bfloat16(s4[i - 524288]);
    else if (i < 688128)           d5[i - 622592] = __float2bfloat16(s5[i - 622592]);
}

// ---------------------------------------------------------------------------
// Depthwise 3x3 conv + BN + residual -> bf16 NHWC mirror (round-15 proven).
// NHWCIN variant stages 4-channel planes from bf16 NHWC (uint2/pixel).
// Register shfl transpose for the NHWC pack; halo-only zero (strided);
// 14.4 KB LDS, 1 barrier. grid (64 cgroups, BB), chunked-XCD remap, block 256.
// ---------------------------------------------------------------------------
#define CPB 4
template <bool WF, bool NHWCIN>
__global__ __launch_bounds__(256) void dw3x3_kernel(
    const float* __restrict__ inF, const bf16* __restrict__ inB,
    const float* __restrict__ w,
    const float* __restrict__ s, const float* __restrict__ b,
    float* __restrict__ out, bf16* __restrict__ outB)
{
    __shared__ float t[CPB][30 * 30];        // padded planes, zero halo

    // chunked-XCD bijective remap: one image's 64 cgroups contiguous per XCD
    int wid = blockIdx.y * gridDim.x + blockIdx.x;         // 0..4095
    int lin = (wid & 7) * 512 + (wid >> 3);                // 4096/8 = 512
    int cg  = lin & 63;
    int n   = lin >> 6;
    int c0  = cg * CPB;

    int tid = threadIdx.x;
    int lm  = tid & 3;                       // this thread's channel (c0+lm)
    float* op = out + ((size_t)n * DIMC + c0) * PP;

    // per-thread channel weights (global scalar loads, L1/L2-cached)
    float w9[9];
#pragma unroll
    for (int i = 0; i < 9; i++) w9[i] = w[(c0 + lm) * 9 + i];
    float sc = s[c0 + lm], bb = b[c0 + lm];

    // zero HALO cells only (116/plane x 4 = 464) — strided over the block
    for (int i = tid; i < 464; i += 256) {
        int plane = i / 116, bq = i - plane * 116;
        int cell;
        if (bq < 30)       cell = bq;                       // top row
        else if (bq < 60)  cell = 870 + (bq - 30);          // bottom row
        else if (bq < 88)  cell = (bq - 60 + 1) * 30;       // left col r=1..28
        else               cell = (bq - 88 + 1) * 30 + 29;  // right col
        t[plane][cell] = 0.f;
    }
    // stage interior
    if (NHWCIN) {
        const unsigned short* ib = (const unsigned short*)inB;
        for (int p = tid; p < PP; p += 256) {
            int h = p / 28, x = p - h * 28;
            union { uint2 u; unsigned short hb[4]; } v;
            v.u = *(const uint2*)&ib[((size_t)n * PP + p) * DIMC + c0];
            int cell = (h + 1) * 30 + (x + 1);
#pragma unroll
            for (int ch = 0; ch < CPB; ch++) t[ch][cell] = bits2f(v.hb[ch]);
        }
    } else {
        const float* ip = inF + ((size_t)n * DIMC + c0) * PP;
        for (int idx = tid; idx < CPB * 196; idx += 256) {
            int ch  = idx / 196;
            int rm  = idx - ch * 196;
            int row = rm / 7, seg = rm - row * 7;
            float4 v = *(const float4*)&ip[ch * PP + row * 28 + seg * 4];
            float* dst = &t[ch][(row + 1) * 30 + seg * 4 + 1];
            dst[0] = v.x; dst[1] = v.y; dst[2] = v.z; dst[3] = v.w;
        }
    }
    __syncthreads();

    // compute: px-major tasks; idx&3 == lm (256 % 4 == 0)
    unsigned short* oBu = (unsigned short*)outB;
    for (int idx = tid; idx < CPB * 196; idx += 256) {
        int rm  = idx >> 2;
        int row = rm / 7, seg = rm - row * 7;
        int x0  = seg * 4;

        float acc[4] = {0.f, 0.f, 0.f, 0.f};
        float ctr[4];
        const float* base = &t[lm][row * 30 + x0];
#pragma unroll
        for (int i = 0; i < 3; i++) {
            float r[6];
#pragma unroll
            for (int k = 0; k < 6; k++) r[k] = base[i * 30 + k];
            if (i == 1) { ctr[0] = r[1]; ctr[1] = r[2]; ctr[2] = r[3]; ctr[3] = r[4]; }
#pragma unroll
            for (int j = 0; j < 3; j++)
#pragma unroll
                for (int q = 0; q < 4; q++)
                    acc[q] += w9[i * 3 + j] * r[j + q];
        }
        float v0 = ctr[0] + acc[0] * sc + bb;
        float v1 = ctr[1] + acc[1] * sc + bb;
        float v2 = ctr[2] + acc[2] * sc + bb;
        float v3 = ctr[3] + acc[3] * sc + bb;

        if (WF) {   // fp32 NCHW write (only when a consumer needs it)
            float4 o; o.x = v0; o.y = v1; o.z = v2; o.w = v3;
            *(float4*)&op[lm * PP + row * 28 + x0] = o;
        }

        // 4x4 transpose across the 4-lane group (static indices only)
        float ea = __shfl_xor((lm & 2) ? v0 : v2, 2);
        float eb = __shfl_xor((lm & 2) ? v1 : v3, 2);
        v0 = (lm & 2) ? ea : v0;  v1 = (lm & 2) ? eb : v1;
        v2 = (lm & 2) ? v2 : ea;  v3 = (lm & 2) ? v3 : eb;
        float ec = __shfl_xor((lm & 1) ? v0 : v1, 1);
        float ed = __shfl_xor((lm & 1) ? v2 : v3, 1);
        v0 = (lm & 1) ? ec : v0;  v1 = (lm & 1) ? v1 : ec;
        v2 = (lm & 1) ? ed : v2;  v3 = (lm & 1) ? v3 : ed;
        // lane q holds channels c0..c0+3 of pixel row*28 + x0 + q
        int p = row * 28 + x0 + lm;
        union { unsigned short h[4]; uint2 u; } pk;
        pk.h[0] = f2bits(v0); pk.h[1] = f2bits(v1);
        pk.h[2] = f2bits(v2); pk.h[3] = f2bits(v3);
        *(uint2*)&oBu[((size_t)n * PP + p) * DIMC + c0] = pk.u;
    }
}

// ---------------------------------------------------------------------------
// Per-head depthwise 5x5 + BN on q channels — round-5 LDS version (proven).
// grid (NHH, BB), block 256, LDS 32 KB.
// ---------------------------------------------------------------------------
__global__ __launch_bounds__(256) void dws5x5_nhwc(
    const bf16* __restrict__ qkv,   // [64][784][384]
    const float* __restrict__ w,    // [64][25]  (hk-major)
    const float* __restrict__ s, const float* __restrict__ b,
    bf16* __restrict__ qout)        // [64][784][64]
{
    __shared__ __align__(16) unsigned short qin[32 * 32 * 16];  // [r][c][ch]
    int hh  = blockIdx.x;
    int n   = blockIdx.y;
    int tid = threadIdx.x;
    const unsigned short* KVu = (const unsigned short*)qkv;

    int kcw = tid & 15;
    int hk  = hh * 16 + kcw;
    float w25[25];
#pragma unroll
    for (int i = 0; i < 25; i++) w25[i] = w[hk * 25 + i];
    float csc = s[hk], cbb = b[hk];

    // zero-fill (halo must be 0), then stage interior
    for (int i = tid; i < 4096; i += 256)
        ((uint4*)qin)[i] = make_uint4(0u, 0u, 0u, 0u);
    __syncthreads();
    for (int idx = tid; idx < 1568; idx += 256) {
        int p = idx >> 1, half = idx & 1;
        int h = p / 28, x = p - h * 28;
        uint4 v = *(const uint4*)&KVu[((size_t)n * PP + p) * 384 + hh * 96 + half * 8];
        *(uint4*)&qin[((h + 2) * 32 + (x + 2)) * 16 + half * 8] = v;
    }
    __syncthreads();

    // compute: 784 px x 16 ch tasks
    for (int idx = tid; idx < 12544; idx += 256) {
        int p = idx >> 4;            // channel == kcw since 256 % 16 == 0
        int h = p / 28, x = p - h * 28;
        float acc = 0.f;
#pragma unroll
        for (int i = 0; i < 5; i++)
#pragma unroll
            for (int j = 0; j < 5; j++)
                acc += w25[i * 5 + j] * bits2f(qin[((h + i) * 32 + (x + j)) * 16 + kcw]);
        qout[((size_t)n * PP + p) * 64 + hk] = __float2bfloat16(acc * csc + cbb);
    }
}

// ---------------------------------------------------------------------------
// 1x1 conv as bf16 MFMA GEMM — ROUND-16: co-tile 128 (2 co-16 blocks/wave);
// resubmitted (round-17 bench was an infra container failure, no signal).
// Doubles MFMA per K-step (14 vs 7; each B-fragment feeds 2 MFMAs) with
// staging traffic and barrier count unchanged -> compute:drain ratio x2.
// RESMODE: 0 none | 1 fp32 NCHW | 2 bf16 NHWC.
// OUTMODE: 0 bf16 NHWC | 1 fp32 NCHW | 2 both.       grid (7, M/128, 64)
// ---------------------------------------------------------------------------
template <bool RELU, int RESMODE, int OUTMODE>
__global__ __launch_bounds__(256) void gemm_mfma(
    const bf16* __restrict__ Wb,    // [M][K] bf16
    const bf16* __restrict__ X,     // [64][784][K] bf16 NHWC
    const float* __restrict__ S, const float* __restrict__ Bb,
    const float* __restrict__ resF, // [64][M][784] fp32 NCHW (RESMODE 1)
    const bf16*  __restrict__ resB, // [64][784][M] bf16 NHWC (RESMODE 2)
    float* __restrict__ outF,       // fp32 NCHW (OUTMODE 1/2)
    bf16*  __restrict__ outB,       // bf16 NHWC (OUTMODE 0/2)
    int M, int K)
{
    // chunked-XCD bijective remap (nwg % 8 == 0 for all instantiations)
    int nwg = gridDim.x * gridDim.y * gridDim.z;
    int wid = (blockIdx.z * gridDim.y + blockIdx.y) * gridDim.x + blockIdx.x;
    int lin = (wid & 7) * (nwg >> 3) + (wid >> 3);
    int yb  = lin % gridDim.y;             // co-tile (fastest: shares X panel)
    int t2  = lin / gridDim.y;
    int xb  = t2 % gridDim.x;              // p-tile
    int n   = t2 / gridDim.x;              // image

    int co0  = yb * 128;
    int p0   = xb * 112;
    int tid  = threadIdx.x;
    int wv   = tid >> 6;
    int ln   = tid & 63;
    int l15  = ln & 15;
    int quad = ln >> 4;

    __shared__ __align__(16) unsigned short Blds[2][112 * 32];  // linear 64B rows

    floatx4 acc[2][7];
#pragma unroll
    for (int g = 0; g < 2; g++)
#pragma unroll
        for (int t = 0; t < 7; t++) acc[g][t] = (floatx4){0.f, 0.f, 0.f, 0.f};

    const bf16* Arow = Wb + (size_t)(co0 + wv * 16 + l15) * K + quad * 8;
    const size_t Aoff = (size_t)64 * K;    // second co-16 group
    const unsigned short* Xb = (const unsigned short*)X + ((size_t)n * PP + p0) * K;

    // staging geometry: issue A covers rows 0..63 (all waves), issue B rows
    // 64..111 (waves 0..2). dest = wave-uniform LDS base + lane*16.
    int rA = wv * 16 + (ln >> 2);            // 0..63
    int rB = 64 + wv * 16 + (ln >> 2);       // 64..111 (wv<3)
    int cA = (ln & 3) ^ ((rA >> 1) & 3);     // pre-swizzled source chunk
    int cB = (ln & 3) ^ ((rB >> 1) & 3);
    const unsigned short* gA = Xb + (size_t)rA * K + cA * 8;
    const unsigned short* gB = Xb + (size_t)rB * K + cB * 8;

    // prologue: stage tile 0
    gll16(gA, &Blds[0][(wv * 16) * 32]);
    if (wv < 3) gll16(gB, &Blds[0][(64 + wv * 16) * 32]);
    short8 af0 = *(const short8*)Arow;
    short8 af1 = *(const short8*)(Arow + Aoff);
    __syncthreads();

    int NT = K >> 5;
    for (int t = 0; t < NT; t++) {
        int cur = t & 1;
        short8 naf0 = af0, naf1 = af1;
        if (t + 1 < NT) {
            gll16(gA + (t + 1) * 32, &Blds[cur ^ 1][(wv * 16) * 32]);
            if (wv < 3) gll16(gB + (t + 1) * 32, &Blds[cur ^ 1][(64 + wv * 16) * 32]);
            naf0 = *(const short8*)(Arow + (t + 1) * 32);
            naf1 = *(const short8*)(Arow + Aoff + (t + 1) * 32);
        }
#pragma unroll
        for (int tt = 0; tt < 7; tt++) {
            int row = tt * 16 + l15;
            short8 bfrag = *(const short8*)
                &Blds[cur][row * 32 + ((quad ^ ((row >> 1) & 3)) * 8)];
            acc[0][tt] = __builtin_amdgcn_mfma_f32_16x16x32_bf16(af0, bfrag, acc[0][tt], 0, 0, 0);
            acc[1][tt] = __builtin_amdgcn_mfma_f32_16x16x32_bf16(af1, bfrag, acc[1][tt], 0, 0, 0);
        }
        af0 = naf0; af1 = naf1;
        __syncthreads();   // vmcnt(0) drain (stage done) + reads of buf[cur] done
    }

#pragma unroll
    for (int g = 0; g < 2; g++) {
        int cobase = co0 + g * 64 + wv * 16 + quad * 4;
        float s4[4], b4[4];
#pragma unroll
        for (int r = 0; r < 4; r++) { s4[r] = S[cobase + r]; b4[r] = Bb[cobase + r]; }

#pragma unroll
        for (int t = 0; t < 7; t++) {
            int p = p0 + t * 16 + l15;   // always < 784
            float resv[4] = {0.f, 0.f, 0.f, 0.f};
            if (RESMODE == 1) {
#pragma unroll
                for (int r = 0; r < 4; r++)
                    resv[r] = resF[((size_t)n * M + cobase + r) * PP + p];
            }
            if (RESMODE == 2) {
                union { uint2 u; unsigned short h[4]; } rr;
                rr.u = *(const uint2*)((const unsigned short*)resB +
                                       ((size_t)n * PP + p) * M + cobase);
#pragma unroll
                for (int r = 0; r < 4; r++) resv[r] = bits2f(rr.h[r]);
            }
            float y[4];
#pragma unroll
            for (int r = 0; r < 4; r++) {
                y[r] = acc[g][t][r] * s4[r] + b4[r];
                if (RELU) y[r] = fmaxf(y[r], 0.f);
                if (RESMODE != 0) y[r] += resv[r];
            }
            if (OUTMODE == 1 || OUTMODE == 2) {
#pragma unroll
                for (int r = 0; r < 4; r++)
                    outF[((size_t)n * M + cobase + r) * PP + p] = y[r];
            }
            if (OUTMODE == 0 || OUTMODE == 2) {
                union { unsigned short h4[4]; uint2 u; } pk;
#pragma unroll
                for (int r = 0; r < 4; r++) pk.h4[r] = f2bits(y[r]);
                *(uint2*)((unsigned short*)outB + ((size_t)n * PP + p) * M + cobase) = pk.u;
            }
        }
    }
}

// ---------------------------------------------------------------------------
// 7x7 window attention — round-1 MFMA version (proven).
// grid (8, 4, 64), block 256.
// ---------------------------------------------------------------------------
__global__ __launch_bounds__(256) void attn_kernel(
    const bf16*  __restrict__ Q,       // [64][784][64] NHWC (hk = hh*16+kc)
    const bf16*  __restrict__ KV,      // [64][784][384] NHWC
    const float* __restrict__ pos,     // [4][49][49]
    bf16* __restrict__ O)              // [64][784][256] NHWC (c = hh*64+d)
{
    int wjp = blockIdx.x & 1, wi = blockIdx.x >> 1;
    int hh  = blockIdx.y, n = blockIdx.z;
    int tid = threadIdx.x;
    int pbase = wi * 7 * 28 + wjp * 14;

    __shared__ __align__(16) char smem[51712];
    unsigned short* qS = (unsigned short*)smem;              // [2][64][40]
    unsigned short* kS = qS + 2 * 64 * 40;                   // [2][64][40]
    unsigned short* pS = (unsigned short*)smem;              // alias: [2][64][72]
    unsigned short* vT = (unsigned short*)(smem + 20480);    // [2][64][72]
    float*          posL = (float*)(smem + 20480 + 18432);   // [64][50]

    const unsigned short* Qu  = (const unsigned short*)Q;
    const unsigned short* KVu = (const unsigned short*)KV;

    // ---- load q, k: 2 bufs x 2 windows x 64 rows x 5 halves (zero-padded) ----
    for (int idx = tid; idx < 1280; idx += 256) {
        int which = idx >= 640 ? 1 : 0;
        int t2 = idx - which * 640;
        int w = t2 / 320, rm = t2 - w * 320;
        int row = rm / 5, half = rm - row * 5;
        uint4 v = make_uint4(0u, 0u, 0u, 0u);
        if (row < 49 && half < 2) {
            int p = pbase + (row / 7) * 28 + w * 7 + (row % 7);
            const unsigned short* src = which
                ? &KVu[((size_t)n * PP + p) * 384 + hh * 96 + 16 + half * 8]
                : &Qu[((size_t)n * PP + p) * 64 + hh * 16 + half * 8];
            v = *(const uint4*)src;
        }
        *(uint4*)((which ? kS : qS) + (w * 64 + row) * 40 + half * 8) = v;
    }
    // ---- stage V transposed: vT[w][d][ki], zero cols for ki >= 49 ----
    for (int idx = tid; idx < 1024; idx += 256) {
        int w = idx >> 9, rm = idx & 511;
        int ki = rm >> 3, dq = rm & 7;
        union { uint4 q; unsigned short h[8]; } v;
        v.q = make_uint4(0u, 0u, 0u, 0u);
        if (ki < 49) {
            int p = pbase + (ki / 7) * 28 + w * 7 + (ki % 7);
            v.q = *(const uint4*)&KVu[((size_t)n * PP + p) * 384 + hh * 96 + 32 + dq * 8];
        }
#pragma unroll
        for (int j = 0; j < 8; j++)
            vT[(w * 64 + dq * 8 + j) * 72 + ki] = v.h[j];
    }
    // ---- stage pos [64][50], zero-padded ----
    for (int idx = tid; idx < 3200; idx += 256) {
        int r = idx / 50, c = idx - r * 50;
        posL[idx] = (r < 49 && c < 49) ? pos[((size_t)hh * 49 + r) * 49 + c] : 0.f;
    }
    __syncthreads();

    int wv = tid >> 6, ln = tid & 63, l15 = ln & 15, quad = ln >> 4;

    // ---- S^T via MFMA + in-register softmax; hold packed bf16 P ----
    uint2 pk[2][4];
#pragma unroll
    for (int w = 0; w < 2; w++) {
        short8 qf = *(const short8*)&qS[(w * 64 + wv * 16 + l15) * 40 + quad * 8];
        floatx4 a4[4];
#pragma unroll
        for (int kt = 0; kt < 4; kt++) {
            short8 kf = *(const short8*)&kS[(w * 64 + kt * 16 + l15) * 40 + quad * 8];
            a4[kt] = __builtin_amdgcn_mfma_f32_16x16x32_bf16(
                kf, qf, (floatx4){0.f, 0.f, 0.f, 0.f}, 0, 0, 0);
        }
        int q = wv * 16 + l15;
        float sv[16];
        float m = -1e30f;
#pragma unroll
        for (int kt = 0; kt < 4; kt++) {
#pragma unroll
            for (int r = 0; r < 4; r++) {
                int ki = kt * 16 + quad * 4 + r;
                float sc = (ki < 49)
                    ? a4[kt][r] * 0.25f + posL[q * 50 + ki]
                    : -1e30f;
                sv[kt * 4 + r] = sc;
                m = fmaxf(m, sc);
            }
        }
        m = fmaxf(m, __shfl_xor(m, 16));
        m = fmaxf(m, __shfl_xor(m, 32));
        float sum = 0.f;
#pragma unroll
        for (int i = 0; i < 16; i++) { sv[i] = __expf(sv[i] - m); sum += sv[i]; }
        sum += __shfl_xor(sum, 16);
        sum += __shfl_xor(sum, 32);
        float inv = 1.f / sum;
#pragma unroll
        for (int kt = 0; kt < 4; kt++) {
            union { uint2 u; unsigned short h[4]; } pku;
#pragma unroll
            for (int r = 0; r < 4; r++) pku.h[r] = f2bits(sv[kt * 4 + r] * inv);
            pk[w][kt] = pku.u;
        }
    }
    __syncthreads();   // all qS/kS MFMA reads done before aliasing writes

    {
        int q = wv * 16 + l15;
#pragma unroll
        for (int w = 0; w < 2; w++)
#pragma unroll
            for (int kt = 0; kt < 4; kt++)
                *(uint2*)&pS[(w * 64 + q) * 72 + kt * 16 + quad * 4] = pk[w][kt];
    }
    __syncthreads();

    // ---- O = relu(P @ V) via MFMA ----
    unsigned short* Ou = (unsigned short*)O;
#pragma unroll
    for (int w = 0; w < 2; w++) {
        short8 af0 = *(const short8*)&pS[(w * 64 + wv * 16 + l15) * 72 + quad * 8];
        short8 af1 = *(const short8*)&pS[(w * 64 + wv * 16 + l15) * 72 + 32 + quad * 8];
#pragma unroll
        for (int dt = 0; dt < 4; dt++) {
            floatx4 oacc = (floatx4){0.f, 0.f, 0.f, 0.f};
            short8 vf0 = *(const short8*)&vT[(w * 64 + dt * 16 + l15) * 72 + quad * 8];
            short8 vf1 = *(const short8*)&vT[(w * 64 + dt * 16 + l15) * 72 + 32 + quad * 8];
            oacc = __builtin_amdgcn_mfma_f32_16x16x32_bf16(af0, vf0, oacc, 0, 0, 0);
            oacc = __builtin_amdgcn_mfma_f32_16x16x32_bf16(af1, vf1, oacc, 0, 0, 0);
#pragma unroll
            for (int r = 0; r < 4; r++) {
                int q = wv * 16 + quad * 4 + r;
                if (q < 49) {
                    int p = pbase + (q / 7) * 28 + w * 7 + (q % 7);
                    Ou[((size_t)n * PP + p) * 256 + hh * 64 + dt * 16 + l15] =
                        f2bits(fmaxf(oacc[r], 0.f));
                }
            }
        }
    }
}

// ---------------------------------------------------------------------------
extern "C" void kernel_launch(void* const* d_in, const int* in_sizes, int n_in,
                              void* d_out, int out_size, void* d_ws, size_t ws_size,
                              hipStream_t stream)
{
    const float* x0     = (const float*)d_in[0];
    const float* dw0_w  = (const float*)d_in[1];
    const float* dw0_s  = (const float*)d_in[2];
    const float* dw0_b  = (const float*)d_in[3];
    const float* dw1_w  = (const float*)d_in[4];
    const float* dw1_s  = (const float*)d_in[5];
    const float* dw1_b  = (const float*)d_in[6];
    const float* f0w1   = (const float*)d_in[7];
    const float* f0s1   = (const float*)d_in[8];
    const float* f0b1   = (const float*)d_in[9];
    const float* f0w2   = (const float*)d_in[10];
    const float* f0s2   = (const float*)d_in[11];
    const float* f0b2   = (const float*)d_in[12];
    const float* f1w1   = (const float*)d_in[13];
    const float* f1s1   = (const float*)d_in[14];
    const float* f1b1   = (const float*)d_in[15];
    const float* f1w2   = (const float*)d_in[16];
    const float* f1s2   = (const float*)d_in[17];
    const float* f1b2   = (const float*)d_in[18];
    const float* qkv_w  = (const float*)d_in[19];
    const float* qkv_s  = (const float*)d_in[20];
    const float* qkv_b  = (const float*)d_in[21];
    const float* dws_w  = (const float*)d_in[22];
    const float* dws_s  = (const float*)d_in[23];
    const float* dws_b  = (const float*)d_in[24];
    const float* proj_w = (const float*)d_in[25];
    const float* proj_s = (const float*)d_in[26];
    const float* proj_b = (const float*)d_in[27];
    const float* pos    = (const float*)d_in[28];

    // -------- workspace (aliased) --------
    const size_t NXB = (size_t)BB * DIMC * PP * 4;    // 51,380,224 B
    char* base  = (char*)d_ws;
    bf16*  X3b  = (bf16*)base;                         // proj out (x3), 25.7 MB
    bf16*  Hb   = (bf16*)(base + NXB);
    bf16*  Qb   = Hb;                                  // alias, disjoint in time
    char*  C_   = base + 2 * NXB;
    bf16*  QKVb = (bf16*)C_;
    bf16*  X1b  = (bf16*)(base + 3 * NXB);             // 25.7 MB
    bf16*  Wc   = (bf16*)(base + 3 * NXB + NXB / 2);
    bf16*  Ob   = (bf16*)d_out;
    float* outp = (float*)d_out;

    bf16* Wf0w1 = Wc;                  // [512][256]
    bf16* Wf0w2 = Wf0w1 + 131072;      // [256][512]
    bf16* Wf1w1 = Wf0w2 + 131072;      // [512][256]
    bf16* Wf1w2 = Wf1w1 + 131072;      // [256][512]
    bf16* Wqkv  = Wf1w2 + 131072;      // [384][256]
    bf16* Wproj = Wqkv + 98304;        // [256][256]

    dim3 blk(256);

    // 0) weights fp32 -> bf16 (single merged launch)
    cvt_all<<<2688, blk, 0, stream>>>(f0w1, Wf0w1, f0w2, Wf0w2,
                                      f1w1, Wf1w1, f1w2, Wf1w2,
                                      qkv_w, Wqkv, proj_w, Wproj);

    // 1) x1 = x + dw0(x) -> bf16 NHWC mirror only (fp32 input)
    dw3x3_kernel<false, false><<<dim3(DIMC / CPB, BB), blk, 0, stream>>>(
        x0, nullptr, dw0_w, dw0_s, dw0_b, nullptr, X1b);

    // 2-3) ffn0: w2 res from X1b (bf16), writes X1b in-place (bf16 only)
    gemm_mfma<true, 0, 0><<<dim3(7, HIDC / 128, BB), blk, 0, stream>>>(
        Wf0w1, X1b, f0s1, f0b1, nullptr, nullptr, nullptr, Hb, HIDC, DIMC);
    gemm_mfma<false, 2, 0><<<dim3(7, DIMC / 128, BB), blk, 0, stream>>>(
        Wf0w2, Hb, f0s2, f0b2, nullptr, X1b, nullptr, X1b, DIMC, HIDC);

    // 4-7) attention; proj res from X1b (x2), OUT bf16 NHWC -> X3b (x3)
    gemm_mfma<false, 0, 0><<<dim3(7, 384 / 128, BB), blk, 0, stream>>>(
        Wqkv, X1b, qkv_s, qkv_b, nullptr, nullptr, nullptr, QKVb, 384, DIMC);
    dws5x5_nhwc<<<dim3(NHH, BB), blk, 0, stream>>>(QKVb, dws_w, dws_s, dws_b, Qb);
    attn_kernel<<<dim3(8, NHH, BB), blk, 0, stream>>>(Qb, QKVb, pos, Ob);
    gemm_mfma<false, 2, 0><<<dim3(7, DIMC / 128, BB), blk, 0, stream>>>(
        Wproj, Ob, proj_s, proj_b, nullptr, X1b, nullptr, X3b, DIMC, DIMC);

    // 8) x4 = x3 + dw1(x3): NHWC bf16 input (X3b), mirror -> X1b
    dw3x3_kernel<false, true><<<dim3(DIMC / CPB, BB), blk, 0, stream>>>(
        nullptr, X3b, dw1_w, dw1_s, dw1_b, nullptr, X1b);

    // 9-10) ffn1: w2 res from X1b, final fp32 NCHW to d_out
    gemm_mfma<true, 0, 0><<<dim3(7, HIDC / 128, BB), blk, 0, stream>>>(
        Wf1w1, X1b, f1s1, f1b1, nullptr, nullptr, nullptr, Hb, HIDC, DIMC);
    gemm_mfma<false, 2, 1><<<dim3(7, DIMC / 128, BB), blk, 0, stream>>>(
        Wf1w2, Hb, f1s2, f1b2, nullptr, X1b, outp, nullptr, DIMC, HIDC);
}